// Round 19
// baseline (759.773 us; speedup 1.0000x reference)
//
#include <hip/hip_runtime.h>
#include <cstdint>
#include <cstddef>

// ---------------- problem constants ----------------
#define T_    2048
#define HID_  4096
#define NH_   32
#define DQ_   256
#define DN_   192
#define DR_   64
#define DV_   256
#define DKV_  512
#define QL_   2048
#define NKV_  576
#define HDQ_  8192         // NH*DQ
#define HDKV_ 14336        // NH*(DN+DV)
#define HDV_  8192         // NH*DV
#define SCALE_ 0.0625f     // 256^-0.5
#define MN5_  8388608      // 2048*4096 (split-K partial size, out-proj)
#define SK5_  2            // split-K factor for out-projection
#define NKC_  2816         // combined q-down + kv-down N (2048 + 576 + 192 pad)
#define PS1_  5767168      // T_*NKC_ (split-K partial stride, combined down-proj)
#define SK1_  4            // split-K factor for combined down-proj

using bf16x8 = __attribute__((ext_vector_type(8))) short;
using f32x4  = __attribute__((ext_vector_type(4))) float;

// ---------------- static device scratch ----------------
__device__ ushort g_hb   [(size_t)T_*HID_];      // hidden bf16
__device__ ushort g_wtc  [(size_t)NKC_*HID_];    // [wq_a | wkv_a]^T combined [N][K] bf16
__device__ ushort g_wtqb [(size_t)HDQ_*QL_];     // wq_b^T
__device__ ushort g_wtkvb[(size_t)HDKV_*DKV_];   // wkv_b^T
__device__ ushort g_wto  [(size_t)HID_*HDV_];    // wo^T
__device__ float  g_qa   [(size_t)T_*QL_];       // q lora summed (fp32)
__device__ ushort g_qn   [(size_t)T_*QL_];       // rmsnorm'd q lora bf16
__device__ ushort g_q    [(size_t)T_*HDQ_];      // q (rope applied in place by q_rope)
__device__ ushort g_kvn  [(size_t)T_*DKV_];      // rmsnorm'd kv latent bf16
__device__ ushort g_kv   [(size_t)T_*HDKV_];     // [t][h*448 + (k_nope|v)] (V region valid)
__device__ ushort g_k    [(size_t)NH_*T_*DQ_];   // K [h][t][256] (k_nope by kv-up, k_pe by kv_norm_rope)
__device__ ushort g_vt   [(size_t)NH_*DV_*T_];   // V^T [h][d][t]
__device__ ushort g_o    [(size_t)T_*HDV_];      // attention out bf16
__device__ float  g_p5   [(size_t)SK1_*PS1_];    // split-K partials (23.1M floats >= SK5_*MN5_)

// ---------------- helpers ----------------
__device__ __forceinline__ float b2f(ushort h){ union{unsigned u; float f;} x; x.u=((unsigned)h)<<16; return x.f; }
__device__ __forceinline__ ushort f2b(float f){ union{float f; unsigned u;} x; x.f=f; unsigned r=x.u + 0x7fffu + ((x.u>>16)&1u); return (ushort)(r>>16); }
__device__ __forceinline__ void storeC(float*  p, float v){ *p = v; }
__device__ __forceinline__ void storeC(ushort* p, float v){ *p = f2b(v); }

#define GLD16(gp, lp) __builtin_amdgcn_global_load_lds( \
    (const __attribute__((address_space(1))) unsigned*)(gp), \
    (__attribute__((address_space(3))) unsigned*)(lp), 16, 0, 0)

// ---------------- hidden convert + ALL weight transposes in one kernel ----------------
// seg -1: hidden fp32->bf16                   8192 blocks
// seg0 wqa[4096x2048]->wtc[0..2048)           4096 (gx=64)
// seg1 wkva[4096x576]->wtc[2048..2816)        1536 (gx=64)
// seg2 wqb[2048x8192]->wtqb                   8192 (gx=32)
// seg3 wkvb[512x14336]->wtkvb                 3584 (gx=8)
// seg4 wo[8192x4096]->wto                     16384 (gx=128)   total 41984
__global__ __launch_bounds__(256) void transpose_all(const float* __restrict__ hs,
                                                     const float* __restrict__ wqa,
                                                     const float* __restrict__ wkva,
                                                     const float* __restrict__ wqb,
                                                     const float* __restrict__ wkvb,
                                                     const float* __restrict__ wo) {
  int bid = blockIdx.x;
  if (bid < 8192) {                      // hidden convert
    size_t i = ((size_t)bid*256 + threadIdx.x)*4;
    float4 v = *(const float4*)(hs + i);
    ushort4 o; o.x=f2b(v.x); o.y=f2b(v.y); o.z=f2b(v.z); o.w=f2b(v.w);
    *(ushort4*)(g_hb + i) = o;
    return;
  }
  bid -= 8192;
  const float* W; ushort* Wt; int K, N, gx;
  if (bid < 4096)       { W=wqa;  Wt=g_wtc;                      K=HID_; N=QL_;   gx=64; }
  else if (bid < 5632)  { W=wkva; Wt=g_wtc+(size_t)QL_*HID_;     K=HID_; N=NKV_;  gx=64;  bid-=4096; }
  else if (bid < 13824) { W=wqb;  Wt=g_wtqb;                     K=QL_;  N=HDQ_;  gx=32;  bid-=5632; }
  else if (bid < 17408) { W=wkvb; Wt=g_wtkvb;                    K=DKV_; N=HDKV_; gx=8;   bid-=13824; }
  else                  { W=wo;   Wt=g_wto;                      K=HDV_; N=HID_;  gx=128; bid-=17408; }
  const int bk = (bid % gx)*64, bn = (bid / gx)*32;

  __shared__ float tile[64][33];
  const int tx = threadIdx.x & 31, ty = threadIdx.x >> 5;
  for (int r = ty; r < 64; r += 8) {
    int n = bn + tx;
    tile[r][tx] = (n < N) ? W[(size_t)(bk + r)*N + n] : 0.f;
  }
  __syncthreads();
  for (int rr = ty; rr < 32; rr += 8) {
    int n = bn + rr;
    unsigned pv = (unsigned)f2b(tile[2*tx][rr]) | ((unsigned)f2b(tile[2*tx+1][rr]) << 16);
    ((unsigned*)(Wt + (size_t)n*K))[(bk>>1) + tx] = pv;
  }
}

// ---------------- 8-phase 256x256 GEMM body (m201-style) ----------------
// EPI: 0 = normal store; 1 = split-K fp32 partials; 2 = kv-route (k_nope->g_k,
// V->g_kv).
template<typename OutT, int S, int EPI>
__device__ __forceinline__ void gemm8_body(ushort* sm,
                                           const ushort* __restrict__ A,
                                           const ushort* __restrict__ Bt,
                                           OutT* __restrict__ C,
                                           int M, int N, int Kfull, int pstride,
                                           int id, int nb) {
  const int tid = threadIdx.x, lane = tid & 63, w = tid >> 6;
  const int wr = w >> 2, wc = w & 3, l15 = lane & 15, l4 = lane >> 4;
  const int swm = (l15 & 7) << 3;
  const int gm = M >> 8, gn = N >> 8;
  const int swz = (id & 7) * (nb >> 3) + (id >> 3);   // XCD swizzle (nb%8==0)
  const int m0 = (swz % gm) << 8;
  const int rest = swz / gm;
  const int n0 = (rest % gn) << 8;
  const int ks = rest / gn;
  const int Ksl = Kfull / S;
  const int kofs = ks * Ksl;
  const int NT = Ksl >> 6;

#define STG_A(tt, qm) do { const int p_=(tt)&1, kb_=kofs+(tt)*64; \
    _Pragma("unroll") \
    for (int i_=0;i_<2;i_++){ \
      const int le_=(i_*512+tid)*8, r_=le_>>6, c_=le_&63; \
      const int tr_=(r_>>6)*128 + (qm)*64 + (r_&63); \
      GLD16(A + (size_t)(m0+tr_)*Kfull + kb_ + (c_ ^ ((r_&7)<<3)), \
            sm + p_*16384 + (qm)*8192 + le_); } } while(0)
#define STG_B(tt, qn) do { const int p_=(tt)&1, kb_=kofs+(tt)*64; \
    _Pragma("unroll") \
    for (int i_=0;i_<2;i_++){ \
      const int le_=(i_*512+tid)*8, r_=le_>>6, c_=le_&63; \
      const int tr_=(r_>>5)*64 + (qn)*32 + (r_&31); \
      GLD16(Bt + (size_t)(n0+tr_)*Kfull + kb_ + (c_ ^ ((r_&7)<<3)), \
            sm + 32768 + p_*16384 + (qn)*8192 + le_); } } while(0)

  f32x4 acc[8][4];
  #pragma unroll
  for (int i=0;i<8;i++)
    #pragma unroll
    for (int j=0;j<4;j++) acc[i][j] = f32x4{0.f,0.f,0.f,0.f};

  STG_A(0,0); STG_B(0,0); STG_A(0,1); STG_B(0,1);
  if (NT > 1) { STG_A(1,0); STG_B(1,0); }
  __builtin_amdgcn_sched_barrier(0);
  if (NT > 1) asm volatile("s_waitcnt vmcnt(4)" ::: "memory");
  else        asm volatile("s_waitcnt vmcnt(0)" ::: "memory");
  __builtin_amdgcn_sched_barrier(0);
  __builtin_amdgcn_s_barrier();

  for (int t = 0; t < NT; ++t) {
    const int p = t & 1;
    const ushort* Ab = sm + p*16384;
    const ushort* Bb = sm + 32768 + p*16384;
    bf16x8 af[4][2], bq0[2][2], bq1[2][2];

    // ---- phase 1: (qm0, qn0) ----
    #pragma unroll
    for (int mi=0;mi<4;mi++)
      #pragma unroll
      for (int k2=0;k2<2;k2++)
        af[mi][k2] = *(const bf16x8*)(Ab + (wr*64 + mi*16 + l15)*64 + ((k2*32 + 8*l4) ^ swm));
    #pragma unroll
    for (int nf=0;nf<2;nf++)
      #pragma unroll
      for (int k2=0;k2<2;k2++)
        bq0[nf][k2] = *(const bf16x8*)(Bb + (wc*32 + nf*16 + l15)*64 + ((k2*32 + 8*l4) ^ swm));
    if (t + 1 < NT) STG_A(t+1, 1);
    __builtin_amdgcn_sched_barrier(0);
    __builtin_amdgcn_s_barrier();
    __builtin_amdgcn_s_setprio(1);
    #pragma unroll
    for (int mi=0;mi<4;mi++)
      #pragma unroll
      for (int nf=0;nf<2;nf++)
        #pragma unroll
        for (int k2=0;k2<2;k2++)
          acc[mi][nf] = __builtin_amdgcn_mfma_f32_16x16x32_bf16(af[mi][k2], bq0[nf][k2], acc[mi][nf], 0,0,0);
    __builtin_amdgcn_s_setprio(0);
    __builtin_amdgcn_sched_barrier(0);
    __builtin_amdgcn_s_barrier();

    // ---- phase 2: (qm0, qn1) ----
    #pragma unroll
    for (int nf=0;nf<2;nf++)
      #pragma unroll
      for (int k2=0;k2<2;k2++)
        bq1[nf][k2] = *(const bf16x8*)(Bb + 8192 + (wc*32 + nf*16 + l15)*64 + ((k2*32 + 8*l4) ^ swm));
    if (t + 1 < NT) STG_B(t+1, 1);
    __builtin_amdgcn_sched_barrier(0);
    __builtin_amdgcn_s_barrier();
    __builtin_amdgcn_s_setprio(1);
    #pragma unroll
    for (int mi=0;mi<4;mi++)
      #pragma unroll
      for (int nf=0;nf<2;nf++)
        #pragma unroll
        for (int k2=0;k2<2;k2++)
          acc[mi][2+nf] = __builtin_amdgcn_mfma_f32_16x16x32_bf16(af[mi][k2], bq1[nf][k2], acc[mi][2+nf], 0,0,0);
    __builtin_amdgcn_s_setprio(0);
    __builtin_amdgcn_sched_barrier(0);
    __builtin_amdgcn_s_barrier();

    // ---- phase 3: (qm1, qn0) ----
    #pragma unroll
    for (int mi=0;mi<4;mi++)
      #pragma unroll
      for (int k2=0;k2<2;k2++)
        af[mi][k2] = *(const bf16x8*)(Ab + 8192 + (wr*64 + mi*16 + l15)*64 + ((k2*32 + 8*l4) ^ swm));
    if (t + 2 < NT) STG_A(t+2, 0);
    __builtin_amdgcn_sched_barrier(0);
    __builtin_amdgcn_s_barrier();
    __builtin_amdgcn_s_setprio(1);
    #pragma unroll
    for (int mi=0;mi<4;mi++)
      #pragma unroll
      for (int nf=0;nf<2;nf++)
        #pragma unroll
        for (int k2=0;k2<2;k2++)
          acc[4+mi][nf] = __builtin_amdgcn_mfma_f32_16x16x32_bf16(af[mi][k2], bq0[nf][k2], acc[4+mi][nf], 0,0,0);
    __builtin_amdgcn_s_setprio(0);
    __builtin_amdgcn_sched_barrier(0);
    __builtin_amdgcn_s_barrier();

    // ---- phase 4: (qm1, qn1) ----
    if (t + 2 < NT) STG_B(t+2, 0);
    __builtin_amdgcn_sched_barrier(0);
    if (t + 2 < NT)      asm volatile("s_waitcnt vmcnt(4)" ::: "memory");
    else if (t + 1 < NT) asm volatile("s_waitcnt vmcnt(0)" ::: "memory");
    __builtin_amdgcn_sched_barrier(0);
    __builtin_amdgcn_s_barrier();
    __builtin_amdgcn_s_setprio(1);
    #pragma unroll
    for (int mi=0;mi<4;mi++)
      #pragma unroll
      for (int nf=0;nf<2;nf++)
        #pragma unroll
        for (int k2=0;k2<2;k2++)
          acc[4+mi][2+nf] = __builtin_amdgcn_mfma_f32_16x16x32_bf16(af[mi][k2], bq1[nf][k2], acc[4+mi][2+nf], 0,0,0);
    __builtin_amdgcn_s_setprio(0);
    __builtin_amdgcn_sched_barrier(0);
    __builtin_amdgcn_s_barrier();
  }
#undef STG_A
#undef STG_B
  asm volatile("s_waitcnt vmcnt(0)" ::: "memory");

  #pragma unroll
  for (int mi=0;mi<8;mi++)
    #pragma unroll
    for (int nj=0;nj<4;nj++) {
      const int row = m0 + wr*128 + mi*16 + l4*4;
      const int col = n0 + wc*64 + nj*16 + l15;
      if (EPI == 2) {
        const int h = col / 448, j = col - h*448;
        #pragma unroll
        for (int r=0;r<4;r++) {
          ushort v = f2b(acc[mi][nj][r]);
          if (j < DN_) g_k[((size_t)h*T_ + row + r)*DQ_ + j] = v;
          else         g_kv[(size_t)(row + r)*HDKV_ + col]   = v;
        }
      } else {
        #pragma unroll
        for (int r=0;r<4;r++) {
          if (S == 1) storeC(&C[(size_t)(row+r)*N + col], acc[mi][nj][r]);
          else ((float*)C)[(size_t)ks*pstride + (size_t)(row+r)*N + col] = acc[mi][nj][r];
        }
      }
    }
}

// standalone gemm8 kernel (down-proj, out-proj)
template<typename OutT, int S, int EPI>
__global__ __launch_bounds__(512, 2) void gemm8(const ushort* __restrict__ A,
                                                const ushort* __restrict__ Bt,
                                                OutT* __restrict__ C,
                                                int M, int N, int Kfull, int pstride) {
  __shared__ ushort sm[65536];
  gemm8_body<OutT,S,EPI>(sm, A, Bt, C, M, N, Kfull, pstride, blockIdx.x, gridDim.x);
}

// fused q-up (blocks 0..255, EPI 0) + kv-up (blocks 256..703, EPI 2)
__global__ __launch_bounds__(512, 2) void gemm_up_dual(const ushort* __restrict__ qn,
                                                       const ushort* __restrict__ wtqb,
                                                       ushort* __restrict__ q,
                                                       const ushort* __restrict__ kvn,
                                                       const ushort* __restrict__ wtkvb) {
  __shared__ ushort sm[65536];
  if (blockIdx.x < 256)
    gemm8_body<ushort,1,0>(sm, qn, wtqb, q, T_, HDQ_, QL_, 0, blockIdx.x, 256);
  else
    gemm8_body<ushort,1,2>(sm, kvn, wtkvb, (ushort*)nullptr, T_, HDKV_, DKV_, 0, blockIdx.x - 256, 448);
}

// ---------------- split-K reduce for out-projection ----------------
__global__ __launch_bounds__(256) void reduce5(const float* __restrict__ p, float* __restrict__ out) {
  size_t i = ((size_t)blockIdx.x*256 + threadIdx.x)*4;
  float4 a = *(const float4*)(p + i);
  #pragma unroll
  for (int s=1; s<SK5_; s++) {
    float4 b = *(const float4*)(p + (size_t)s*MN5_ + i);
    a.x+=b.x; a.y+=b.y; a.z+=b.z; a.w+=b.w;
  }
  *(float4*)(out + i) = a;
}

// ---------------- rmsnorm for q lora (fused SK1_-way reduce, combined partials) ----------------
__global__ __launch_bounds__(256) void rmsnorm_q(const float* __restrict__ p,
                                                 const float* __restrict__ wln) {
  const int row = blockIdx.x;
  const float* x = p + (size_t)row*NKC_;
  float* xo = g_qa + (size_t)row*QL_;
  float ss = 0.f;
  for (int i = threadIdx.x; i < QL_/4; i += 256) {
    float4 v = *(const float4*)(x + i*4);
    #pragma unroll
    for (int s=1; s<SK1_; s++) {
      float4 b = *(const float4*)(x + (size_t)s*PS1_ + i*4);
      v.x+=b.x; v.y+=b.y; v.z+=b.z; v.w+=b.w;
    }
    ((float4*)xo)[i] = v;
    ss += v.x*v.x + v.y*v.y + v.z*v.z + v.w*v.w;
  }
  #pragma unroll
  for (int o=32;o>=1;o>>=1) ss += __shfl_xor(ss, o);
  __shared__ float sr[4];
  if ((threadIdx.x & 63) == 0) sr[threadIdx.x>>6] = ss;
  __syncthreads();
  float rs = rsqrtf((sr[0]+sr[1]+sr[2]+sr[3])/(float)QL_ + 1e-6f);
  for (int i = threadIdx.x; i < QL_; i += 256)
    g_qn[(size_t)row*QL_ + i] = f2b(xo[i]*rs*wln[i]);
}

// ---------------- kv latent rmsnorm + k_pe rope (writes k_pe into g_k for all heads) ----------------
__global__ __launch_bounds__(256) void kv_norm_rope(const float* __restrict__ p,
                                                    const float* __restrict__ wln,
                                                    const int* __restrict__ pos) {
  const int t = blockIdx.x;
  const float* base = p + (size_t)t*NKC_ + QL_;   // combined cols 2048..2623
  __shared__ float lat[NKV_];
  float ss = 0.f;
  for (int i = threadIdx.x; i < NKV_; i += 256) {
    float v = base[i];
    #pragma unroll
    for (int s=1; s<SK1_; s++) v += base[(size_t)s*PS1_ + i];
    lat[i] = v;
    if (i < DKV_) ss += v*v;
  }
  #pragma unroll
  for (int o=32;o>=1;o>>=1) ss += __shfl_xor(ss, o);
  __shared__ float sr[4];
  if ((threadIdx.x & 63) == 0) sr[threadIdx.x>>6] = ss;
  __syncthreads();                                 // covers lat[] too
  float rs = rsqrtf((sr[0]+sr[1]+sr[2]+sr[3])/(float)DKV_ + 1e-6f);
  for (int i = threadIdx.x; i < DKV_; i += 256)
    g_kvn[(size_t)t*DKV_ + i] = f2b(lat[i]*rs*wln[i]);
  // roped k_pe -> g_k[h][t][192..256) for ALL heads
  {
    const int i = threadIdx.x & 31, hb = threadIdx.x >> 5;   // 8 h-groups
    float pp = (float)pos[t];
    float ang = pp * powf(10000.f, -(float)i/32.f);
    float c = cosf(ang), s = sinf(ang);
    float x1 = lat[DKV_ + i], x2 = lat[DKV_ + 32 + i];
    ushort k1 = f2b(x1*c - x2*s);
    ushort k2 = f2b(x2*c + x1*s);
    #pragma unroll
    for (int hh = 0; hh < 4; ++hh) {
      const int h = hb + hh*8;
      g_k[((size_t)h*T_ + t)*DQ_ + DN_ + i]      = k1;
      g_k[((size_t)h*T_ + t)*DQ_ + DN_ + 32 + i] = k2;
    }
  }
}

// ---------------- q rope (in place on g_q) ----------------
__global__ __launch_bounds__(256) void q_rope(const int* __restrict__ pos) {
  const int t = blockIdx.x;
  __shared__ float cs[32], sn[32];
  if (threadIdx.x < 32) {
    const int i = threadIdx.x;
    float p = (float)pos[t];
    float ang = p * powf(10000.f, -(float)i/32.f);
    cs[i] = cosf(ang); sn[i] = sinf(ang);
  }
  __syncthreads();
  for (int e = threadIdx.x; e < NH_*32; e += 256) {
    const int h = e >> 5, i = e & 31;
    ushort* qp = g_q + (size_t)t*HDQ_ + h*DQ_ + DN_;
    float x1 = b2f(qp[i]), x2 = b2f(qp[32 + i]);
    qp[i]      = f2b(x1*cs[i] - x2*sn[i]);
    qp[32 + i] = f2b(x2*cs[i] + x1*sn[i]);
  }
}

// ---------------- build V^T [h][d][t] (64-row tiles via LDS) ----------------
__global__ __launch_bounds__(256) void build_vt() {
  const int h = blockIdx.x, tt = blockIdx.y;
  __shared__ ushort tile[64*272];
  const int tid = threadIdx.x;
  #pragma unroll
  for (int p=0;p<8;p++) {
    int le = (p*256+tid)*8;
    int tl = le >> 8, d = le & 255;
    uint4 v = *(const uint4*)(g_kv + (size_t)(tt*64 + tl)*HDKV_ + h*448 + DN_ + d);
    *(uint4*)(tile + tl*272 + d) = v;
  }
  __syncthreads();
  #pragma unroll
  for (int p=0;p<8;p++) {
    int le = (p*256+tid)*8;
    int d = le >> 6, tl0 = le & 63;
    ushort tmp[8];
    #pragma unroll
    for (int j=0;j<8;j++) tmp[j] = tile[(tl0+j)*272 + d];
    *(uint4*)(g_vt + ((size_t)h*DV_ + d)*T_ + tt*64 + tl0) = *(const uint4*)tmp;
  }
}

// ---------------- flash attention ----------------
// R19: SEPARATE K and V LDS buffers (72KB; 2 blocks/CU unchanged — VGPR 168
// is the cap, LDS was slack) -> 2-barrier tile loop. The old 4-barrier
// structure existed only because K/V shared one buffer (V overwrote K
// mid-tile). Now: stage K[t+1]+V[t+1] together at tile end; top of tile =
// vmcnt(0)+barrier; body runs QK/softmax/PV with no global waits; bottom =
// lgkmcnt(0)+barrier (WAR before restaging). Exposed staging latency sits on
// the loop-back edge (R6/R8/R10: latency exposure ~free at this occupancy).
// HARD RULES: no min-waves launch bound (R7/R9/R11 spill collapse); no
// per-lane transcendental prologue (R16 regression).
__global__ __launch_bounds__(256) void attn_kernel() {
  __shared__ ushort Ks [64*256];       // 32KB K tile [kv][d], swizzled
  __shared__ ushort Vts[256*64];       // 32KB V^T tile [d][kv], swizzled
  __shared__ ushort Pl[4][16][64];     // 8KB per-wave P [q-local][kv]
  const int h = blockIdx.x;
  const int qt = (gridDim.y - 1) - blockIdx.y;     // heavy tiles first
  const int tid = threadIdx.x, lane = tid & 63, w = tid >> 6;
  const int l15 = lane & 15, l4 = lane >> 4;
  const int swm = (l15 & 7) << 3;      // swizzle mask (row = l15 for Pl)

  const ushort* Kh = g_k  + (size_t)h*T_*DQ_;
  const ushort* Vh = g_vt + (size_t)h*DV_*T_;

#define STAGE_K(kt_) do { \
    const ushort* ks_ = Kh + (size_t)(kt_)*64*DQ_; \
    _Pragma("unroll") \
    for (int c_=0;c_<8;c_++){ int le_=(c_*256+tid)*8, r_=le_>>8, co_=le_&255; \
      GLD16(ks_ + r_*256 + (co_ ^ ((r_&7)<<3)), Ks+le_); } } while(0)
#define STAGE_V(kt_) do { \
    _Pragma("unroll") \
    for (int c_=0;c_<8;c_++){ int le_=(c_*256+tid)*8, d_=le_>>6, kv_=le_&63; \
      GLD16(Vh + (size_t)d_*T_ + (kt_)*64 + (kv_ ^ ((d_&7)<<3)), Vts+le_); } } while(0)

  const int q0 = qt*64;
  const int qrow = q0 + w*16 + l15;                // this lane's q-row

  bf16x8 qf[8];
  {
    const ushort* qb = g_q + (size_t)qrow*HDQ_ + h*DQ_;
    #pragma unroll
    for (int g=0; g<8; g++) qf[g] = *(const bf16x8*)(qb + 32*g + 8*l4);
  }
  f32x4 acc[16];
  #pragma unroll
  for (int i=0;i<16;i++) acc[i] = f32x4{0.f,0.f,0.f,0.f};
  float m_r = -1e30f, l_r = 0.f;

  STAGE_K(0);
  STAGE_V(0);

  for (int kt = 0; kt <= qt; ++kt) {
    __builtin_amdgcn_sched_barrier(0);
    asm volatile("s_waitcnt vmcnt(0)" ::: "memory");
    __builtin_amdgcn_sched_barrier(0);
    __builtin_amdgcn_s_barrier();                // K[kt] and V[kt] visible

    // S^T via swapped operands: lane gets S[q=l15][kv=fn*16+l4*4+r]
    f32x4 s[4];
    #pragma unroll
    for (int fn=0; fn<4; fn++) s[fn] = f32x4{0.f,0.f,0.f,0.f};
    __builtin_amdgcn_s_setprio(1);
    #pragma unroll
    for (int g=0; g<8; g++)
      #pragma unroll
      for (int fn=0; fn<4; fn++) {
        bf16x8 kf = *(const bf16x8*)(Ks + (fn*16 + l15)*256 + ((32*g + 8*l4) ^ swm));
        s[fn] = __builtin_amdgcn_mfma_f32_16x16x32_bf16(kf, qf[g], s[fn], 0,0,0);
      }
    __builtin_amdgcn_s_setprio(0);

    // causal mask (diagonal tile only): kv index is lane-register-local
    if (kt == qt) {
      #pragma unroll
      for (int fn=0; fn<4; fn++)
        #pragma unroll
        for (int r=0;r<4;r++) {
          int kv = kt*64 + fn*16 + l4*4 + r;
          if (kv > qrow) s[fn][r] = -1e30f;
        }
    }

    // online softmax — one q-row per lane: local 16-tree + 2 shuffles
    float mx = s[0][0];
    #pragma unroll
    for (int fn=0; fn<4; fn++)
      #pragma unroll
      for (int r=0;r<4;r++) mx = fmaxf(mx, s[fn][r]);
    mx = fmaxf(mx, __shfl_xor(mx, 16));
    mx = fmaxf(mx, __shfl_xor(mx, 32));
    mx *= SCALE_;
    if (__any(mx > m_r)) {             // rescale only when some row max grew
      float mn = fmaxf(m_r, mx);
      float sc = __expf(m_r - mn);
      m_r = mn;
      l_r *= sc;
      #pragma unroll
      for (int fd=0; fd<16; fd++)
        #pragma unroll
        for (int r=0;r<4;r++) acc[fd][r] *= sc;
    }
    float ssum = 0.f;
    #pragma unroll
    for (int fn=0; fn<4; fn++)
      #pragma unroll
      for (int r=0;r<4;r++) {
        float p = __expf(fmaf(s[fn][r], SCALE_, -m_r));
        s[fn][r] = p; ssum += p;
      }
    ssum += __shfl_xor(ssum, 16);
    ssum += __shfl_xor(ssum, 32);
    l_r += ssum;

    // P -> LDS (intra-wave), 8B vector writes, swizzled on row l15
    #pragma unroll
    for (int fn=0; fn<4; fn++) {
      ushort4 pw;
      pw.x = f2b(s[fn][0]); pw.y = f2b(s[fn][1]);
      pw.z = f2b(s[fn][2]); pw.w = f2b(s[fn][3]);
      *(ushort4*)(&Pl[w][l15][(fn*16 + l4*4) ^ swm]) = pw;
    }

    // O^T += V^T P^T  (swapped): lane gets O[q=l15][d=fd*16+l4*4+r]
    __builtin_amdgcn_s_setprio(1);
    #pragma unroll
    for (int s2=0; s2<2; s2++) {
      bf16x8 pa = *(const bf16x8*)(&Pl[w][l15][(s2*32 + 8*l4) ^ swm]);
      #pragma unroll
      for (int fd=0; fd<16; fd++) {
        bf16x8 vb = *(const bf16x8*)(Vts + (fd*16 + l15)*64 + ((s2*32 + 8*l4) ^ swm));
        acc[fd] = __builtin_amdgcn_mfma_f32_16x16x32_bf16(vb, pa, acc[fd], 0,0,0);
      }
    }
    __builtin_amdgcn_s_setprio(0);
    asm volatile("s_waitcnt lgkmcnt(0)" ::: "memory");
    __builtin_amdgcn_sched_barrier(0);
    __builtin_amdgcn_s_barrier();                // all waves done reading Ks/Vts
    if (kt < qt) { STAGE_K(kt+1); STAGE_V(kt+1); }
    __builtin_amdgcn_sched_barrier(0);
  }

  l_r = 1.f / l_r;
  #pragma unroll
  for (int fd=0; fd<16; fd++) {
    ushort4 ow;
    ow.x = f2b(acc[fd][0] * l_r); ow.y = f2b(acc[fd][1] * l_r);
    ow.z = f2b(acc[fd][2] * l_r); ow.w = f2b(acc[fd][3] * l_r);
    *(ushort4*)(g_o + (size_t)qrow*HDV_ + h*DV_ + fd*16 + l4*4) = ow;
  }
#undef STAGE_K
#undef STAGE_V
}

// ---------------- host launch ----------------
extern "C" void kernel_launch(void* const* d_in, const int* in_sizes, int n_in,
                              void* d_out, int out_size, void* d_ws, size_t ws_size,
                              hipStream_t stream) {
  (void)in_sizes; (void)n_in; (void)d_ws; (void)ws_size; (void)out_size;
  const float* hs    = (const float*)d_in[0];
  const int*   pos   = (const int*)  d_in[1];
  const float* wqa   = (const float*)d_in[2];
  const float* qlnw  = (const float*)d_in[3];
  const float* wqb   = (const float*)d_in[4];
  const float* wkva  = (const float*)d_in[5];
  const float* kvlnw = (const float*)d_in[6];
  const float* wkvb  = (const float*)d_in[7];
  const float* wo    = (const float*)d_in[8];
  float* out = (float*)d_out;

  void *p_hb, *p_wtc, *p_wtqb, *p_wtkvb, *p_wto;
  void *p_qn, *p_q, *p_kvn, *p_kv, *p_o, *p_p5;
  hipGetSymbolAddress(&p_hb,    HIP_SYMBOL(g_hb));
  hipGetSymbolAddress(&p_wtc,   HIP_SYMBOL(g_wtc));
  hipGetSymbolAddress(&p_wtqb,  HIP_SYMBOL(g_wtqb));
  hipGetSymbolAddress(&p_wtkvb, HIP_SYMBOL(g_wtkvb));
  hipGetSymbolAddress(&p_wto,   HIP_SYMBOL(g_wto));
  hipGetSymbolAddress(&p_qn,    HIP_SYMBOL(g_qn));
  hipGetSymbolAddress(&p_q,     HIP_SYMBOL(g_q));
  hipGetSymbolAddress(&p_kvn,   HIP_SYMBOL(g_kvn));
  hipGetSymbolAddress(&p_kv,    HIP_SYMBOL(g_kv));
  hipGetSymbolAddress(&p_o,     HIP_SYMBOL(g_o));
  hipGetSymbolAddress(&p_p5,    HIP_SYMBOL(g_p5));

  // 1) hidden convert + ALL weight transposes (one kernel)
  transpose_all<<<41984, 256, 0, stream>>>(hs, wqa, wkva, wqb, wkvb, wo);

  // 2) combined down-projection (q-lora + kv-latent), split-K=4; reduces fused
  gemm8<float,SK1_,1><<<(T_/256)*(NKC_/256)*SK1_, 512, 0, stream>>>((const ushort*)p_hb, (const ushort*)p_wtc, (float*)p_p5, T_, NKC_, HID_, PS1_);
  rmsnorm_q<<<T_, 256, 0, stream>>>((const float*)p_p5, qlnw);
  kv_norm_rope<<<T_, 256, 0, stream>>>((const float*)p_p5, kvlnw, pos);

  // 3) fused up-projections: q-up (256 blocks) + kv-up (448 blocks, k/V routed)
  gemm_up_dual<<<704, 512, 0, stream>>>((const ushort*)p_qn, (const ushort*)p_wtqb, (ushort*)p_q,
                                        (const ushort*)p_kvn, (const ushort*)p_wtkvb);
  q_rope<<<T_, 256, 0, stream>>>(pos);

  // 4) attention prep + attention (one q-tile per block, heavy first)
  build_vt<<<dim3(NH_, T_/64), 256, 0, stream>>>();
  attn_kernel<<<dim3(NH_, 32), 256, 0, stream>>>();

  // 5) output projection (split-K=2) + reduce
  gemm8<float,SK5_,1><<<(T_/256)*(HID_/256)*SK5_, 512, 0, stream>>>((const ushort*)p_o, (const ushort*)p_wto, (float*)p_p5, T_, HID_, HDV_, MN5_);
  reduce5<<<MN5_/1024, 256, 0, stream>>>((const float*)p_p5, out);
}

// Round 20
// 744.042 us; speedup vs baseline: 1.0211x; 1.0211x over previous
//
#include <hip/hip_runtime.h>
#include <cstdint>
#include <cstddef>

// ---------------- problem constants ----------------
#define T_    2048
#define HID_  4096
#define NH_   32
#define DQ_   256
#define DN_   192
#define DR_   64
#define DV_   256
#define DKV_  512
#define QL_   2048
#define NKV_  576
#define HDQ_  8192         // NH*DQ
#define HDKV_ 14336        // NH*(DN+DV)
#define HDV_  8192         // NH*DV
#define SCALE_ 0.0625f     // 256^-0.5
#define MN5_  8388608      // 2048*4096 (split-K partial size, out-proj)
#define SK5_  2            // split-K factor for out-projection
#define NKC_  2816         // combined q-down + kv-down N (2048 + 576 + 192 pad)
#define PS1_  5767168      // T_*NKC_ (split-K partial stride, combined down-proj)
#define SK1_  4            // split-K factor for combined down-proj

using bf16x8 = __attribute__((ext_vector_type(8))) short;
using f32x4  = __attribute__((ext_vector_type(4))) float;

// ---------------- static device scratch ----------------
__device__ ushort g_hb   [(size_t)T_*HID_];      // hidden bf16
__device__ ushort g_wtc  [(size_t)NKC_*HID_];    // [wq_a | wkv_a]^T combined [N][K] bf16
__device__ ushort g_wtqb [(size_t)HDQ_*QL_];     // wq_b^T
__device__ ushort g_wtkvb[(size_t)HDKV_*DKV_];   // wkv_b^T
__device__ ushort g_wto  [(size_t)HID_*HDV_];    // wo^T
__device__ float  g_qa   [(size_t)T_*QL_];       // q lora summed (fp32)
__device__ ushort g_qn   [(size_t)T_*QL_];       // rmsnorm'd q lora bf16
__device__ ushort g_q    [(size_t)T_*HDQ_];      // q (rope applied in place by q_rope)
__device__ ushort g_kvn  [(size_t)T_*DKV_];      // rmsnorm'd kv latent bf16
__device__ ushort g_kv   [(size_t)T_*HDKV_];     // [t][h*448 + (k_nope|v)] (V region valid)
__device__ ushort g_k    [(size_t)NH_*T_*DQ_];   // K [h][t][256] (k_nope by kv-up, k_pe by kv_norm_rope)
__device__ ushort g_vt   [(size_t)NH_*DV_*T_];   // V^T [h][d][t]
__device__ ushort g_o    [(size_t)T_*HDV_];      // attention out bf16
__device__ float  g_p5   [(size_t)SK1_*PS1_];    // split-K partials (23.1M floats >= SK5_*MN5_)

// ---------------- helpers ----------------
__device__ __forceinline__ float b2f(ushort h){ union{unsigned u; float f;} x; x.u=((unsigned)h)<<16; return x.f; }
__device__ __forceinline__ ushort f2b(float f){ union{float f; unsigned u;} x; x.f=f; unsigned r=x.u + 0x7fffu + ((x.u>>16)&1u); return (ushort)(r>>16); }
__device__ __forceinline__ void storeC(float*  p, float v){ *p = v; }
__device__ __forceinline__ void storeC(ushort* p, float v){ *p = f2b(v); }

#define GLD16(gp, lp) __builtin_amdgcn_global_load_lds( \
    (const __attribute__((address_space(1))) unsigned*)(gp), \
    (__attribute__((address_space(3))) unsigned*)(lp), 16, 0, 0)

// ---------------- hidden convert + ALL weight transposes in one kernel ----------------
__global__ __launch_bounds__(256) void transpose_all(const float* __restrict__ hs,
                                                     const float* __restrict__ wqa,
                                                     const float* __restrict__ wkva,
                                                     const float* __restrict__ wqb,
                                                     const float* __restrict__ wkvb,
                                                     const float* __restrict__ wo) {
  int bid = blockIdx.x;
  if (bid < 8192) {                      // hidden convert
    size_t i = ((size_t)bid*256 + threadIdx.x)*4;
    float4 v = *(const float4*)(hs + i);
    ushort4 o; o.x=f2b(v.x); o.y=f2b(v.y); o.z=f2b(v.z); o.w=f2b(v.w);
    *(ushort4*)(g_hb + i) = o;
    return;
  }
  bid -= 8192;
  const float* W; ushort* Wt; int K, N, gx;
  if (bid < 4096)       { W=wqa;  Wt=g_wtc;                      K=HID_; N=QL_;   gx=64; }
  else if (bid < 5632)  { W=wkva; Wt=g_wtc+(size_t)QL_*HID_;     K=HID_; N=NKV_;  gx=64;  bid-=4096; }
  else if (bid < 13824) { W=wqb;  Wt=g_wtqb;                     K=QL_;  N=HDQ_;  gx=32;  bid-=5632; }
  else if (bid < 17408) { W=wkvb; Wt=g_wtkvb;                    K=DKV_; N=HDKV_; gx=8;   bid-=13824; }
  else                  { W=wo;   Wt=g_wto;                      K=HDV_; N=HID_;  gx=128; bid-=17408; }
  const int bk = (bid % gx)*64, bn = (bid / gx)*32;

  __shared__ float tile[64][33];
  const int tx = threadIdx.x & 31, ty = threadIdx.x >> 5;
  for (int r = ty; r < 64; r += 8) {
    int n = bn + tx;
    tile[r][tx] = (n < N) ? W[(size_t)(bk + r)*N + n] : 0.f;
  }
  __syncthreads();
  for (int rr = ty; rr < 32; rr += 8) {
    int n = bn + rr;
    unsigned pv = (unsigned)f2b(tile[2*tx][rr]) | ((unsigned)f2b(tile[2*tx+1][rr]) << 16);
    ((unsigned*)(Wt + (size_t)n*K))[(bk>>1) + tx] = pv;
  }
}

// ---------------- 8-phase 256x256 GEMM body (m201-style) ----------------
// EPI: 0 = normal store; 1 = split-K fp32 partials; 2 = kv-route (k_nope->g_k,
// V->g_kv).
template<typename OutT, int S, int EPI>
__device__ __forceinline__ void gemm8_body(ushort* sm,
                                           const ushort* __restrict__ A,
                                           const ushort* __restrict__ Bt,
                                           OutT* __restrict__ C,
                                           int M, int N, int Kfull, int pstride,
                                           int id, int nb) {
  const int tid = threadIdx.x, lane = tid & 63, w = tid >> 6;
  const int wr = w >> 2, wc = w & 3, l15 = lane & 15, l4 = lane >> 4;
  const int swm = (l15 & 7) << 3;
  const int gm = M >> 8, gn = N >> 8;
  const int swz = (id & 7) * (nb >> 3) + (id >> 3);   // XCD swizzle (nb%8==0)
  const int m0 = (swz % gm) << 8;
  const int rest = swz / gm;
  const int n0 = (rest % gn) << 8;
  const int ks = rest / gn;
  const int Ksl = Kfull / S;
  const int kofs = ks * Ksl;
  const int NT = Ksl >> 6;

#define STG_A(tt, qm) do { const int p_=(tt)&1, kb_=kofs+(tt)*64; \
    _Pragma("unroll") \
    for (int i_=0;i_<2;i_++){ \
      const int le_=(i_*512+tid)*8, r_=le_>>6, c_=le_&63; \
      const int tr_=(r_>>6)*128 + (qm)*64 + (r_&63); \
      GLD16(A + (size_t)(m0+tr_)*Kfull + kb_ + (c_ ^ ((r_&7)<<3)), \
            sm + p_*16384 + (qm)*8192 + le_); } } while(0)
#define STG_B(tt, qn) do { const int p_=(tt)&1, kb_=kofs+(tt)*64; \
    _Pragma("unroll") \
    for (int i_=0;i_<2;i_++){ \
      const int le_=(i_*512+tid)*8, r_=le_>>6, c_=le_&63; \
      const int tr_=(r_>>5)*64 + (qn)*32 + (r_&31); \
      GLD16(Bt + (size_t)(n0+tr_)*Kfull + kb_ + (c_ ^ ((r_&7)<<3)), \
            sm + 32768 + p_*16384 + (qn)*8192 + le_); } } while(0)

  f32x4 acc[8][4];
  #pragma unroll
  for (int i=0;i<8;i++)
    #pragma unroll
    for (int j=0;j<4;j++) acc[i][j] = f32x4{0.f,0.f,0.f,0.f};

  STG_A(0,0); STG_B(0,0); STG_A(0,1); STG_B(0,1);
  if (NT > 1) { STG_A(1,0); STG_B(1,0); }
  __builtin_amdgcn_sched_barrier(0);
  if (NT > 1) asm volatile("s_waitcnt vmcnt(4)" ::: "memory");
  else        asm volatile("s_waitcnt vmcnt(0)" ::: "memory");
  __builtin_amdgcn_sched_barrier(0);
  __builtin_amdgcn_s_barrier();

  for (int t = 0; t < NT; ++t) {
    const int p = t & 1;
    const ushort* Ab = sm + p*16384;
    const ushort* Bb = sm + 32768 + p*16384;
    bf16x8 af[4][2], bq0[2][2], bq1[2][2];

    // ---- phase 1: (qm0, qn0) ----
    #pragma unroll
    for (int mi=0;mi<4;mi++)
      #pragma unroll
      for (int k2=0;k2<2;k2++)
        af[mi][k2] = *(const bf16x8*)(Ab + (wr*64 + mi*16 + l15)*64 + ((k2*32 + 8*l4) ^ swm));
    #pragma unroll
    for (int nf=0;nf<2;nf++)
      #pragma unroll
      for (int k2=0;k2<2;k2++)
        bq0[nf][k2] = *(const bf16x8*)(Bb + (wc*32 + nf*16 + l15)*64 + ((k2*32 + 8*l4) ^ swm));
    if (t + 1 < NT) STG_A(t+1, 1);
    __builtin_amdgcn_sched_barrier(0);
    __builtin_amdgcn_s_barrier();
    __builtin_amdgcn_s_setprio(1);
    #pragma unroll
    for (int mi=0;mi<4;mi++)
      #pragma unroll
      for (int nf=0;nf<2;nf++)
        #pragma unroll
        for (int k2=0;k2<2;k2++)
          acc[mi][nf] = __builtin_amdgcn_mfma_f32_16x16x32_bf16(af[mi][k2], bq0[nf][k2], acc[mi][nf], 0,0,0);
    __builtin_amdgcn_s_setprio(0);
    __builtin_amdgcn_sched_barrier(0);
    __builtin_amdgcn_s_barrier();

    // ---- phase 2: (qm0, qn1) ----
    #pragma unroll
    for (int nf=0;nf<2;nf++)
      #pragma unroll
      for (int k2=0;k2<2;k2++)
        bq1[nf][k2] = *(const bf16x8*)(Bb + 8192 + (wc*32 + nf*16 + l15)*64 + ((k2*32 + 8*l4) ^ swm));
    if (t + 1 < NT) STG_B(t+1, 1);
    __builtin_amdgcn_sched_barrier(0);
    __builtin_amdgcn_s_barrier();
    __builtin_amdgcn_s_setprio(1);
    #pragma unroll
    for (int mi=0;mi<4;mi++)
      #pragma unroll
      for (int nf=0;nf<2;nf++)
        #pragma unroll
        for (int k2=0;k2<2;k2++)
          acc[mi][2+nf] = __builtin_amdgcn_mfma_f32_16x16x32_bf16(af[mi][k2], bq1[nf][k2], acc[mi][2+nf], 0,0,0);
    __builtin_amdgcn_s_setprio(0);
    __builtin_amdgcn_sched_barrier(0);
    __builtin_amdgcn_s_barrier();

    // ---- phase 3: (qm1, qn0) ----
    #pragma unroll
    for (int mi=0;mi<4;mi++)
      #pragma unroll
      for (int k2=0;k2<2;k2++)
        af[mi][k2] = *(const bf16x8*)(Ab + 8192 + (wr*64 + mi*16 + l15)*64 + ((k2*32 + 8*l4) ^ swm));
    if (t + 2 < NT) STG_A(t+2, 0);
    __builtin_amdgcn_sched_barrier(0);
    __builtin_amdgcn_s_barrier();
    __builtin_amdgcn_s_setprio(1);
    #pragma unroll
    for (int mi=0;mi<4;mi++)
      #pragma unroll
      for (int nf=0;nf<2;nf++)
        #pragma unroll
        for (int k2=0;k2<2;k2++)
          acc[4+mi][nf] = __builtin_amdgcn_mfma_f32_16x16x32_bf16(af[mi][k2], bq0[nf][k2], acc[4+mi][nf], 0,0,0);
    __builtin_amdgcn_s_setprio(0);
    __builtin_amdgcn_sched_barrier(0);
    __builtin_amdgcn_s_barrier();

    // ---- phase 4: (qm1, qn1) ----
    if (t + 2 < NT) STG_B(t+2, 0);
    __builtin_amdgcn_sched_barrier(0);
    if (t + 2 < NT)      asm volatile("s_waitcnt vmcnt(4)" ::: "memory");
    else if (t + 1 < NT) asm volatile("s_waitcnt vmcnt(0)" ::: "memory");
    __builtin_amdgcn_sched_barrier(0);
    __builtin_amdgcn_s_barrier();
    __builtin_amdgcn_s_setprio(1);
    #pragma unroll
    for (int mi=0;mi<4;mi++)
      #pragma unroll
      for (int nf=0;nf<2;nf++)
        #pragma unroll
        for (int k2=0;k2<2;k2++)
          acc[4+mi][2+nf] = __builtin_amdgcn_mfma_f32_16x16x32_bf16(af[mi][k2], bq1[nf][k2], acc[4+mi][2+nf], 0,0,0);
    __builtin_amdgcn_s_setprio(0);
    __builtin_amdgcn_sched_barrier(0);
    __builtin_amdgcn_s_barrier();
  }
#undef STG_A
#undef STG_B
  asm volatile("s_waitcnt vmcnt(0)" ::: "memory");

  #pragma unroll
  for (int mi=0;mi<8;mi++)
    #pragma unroll
    for (int nj=0;nj<4;nj++) {
      const int row = m0 + wr*128 + mi*16 + l4*4;
      const int col = n0 + wc*64 + nj*16 + l15;
      if (EPI == 2) {
        const int h = col / 448, j = col - h*448;
        #pragma unroll
        for (int r=0;r<4;r++) {
          ushort v = f2b(acc[mi][nj][r]);
          if (j < DN_) g_k[((size_t)h*T_ + row + r)*DQ_ + j] = v;
          else         g_kv[(size_t)(row + r)*HDKV_ + col]   = v;
        }
      } else {
        #pragma unroll
        for (int r=0;r<4;r++) {
          if (S == 1) storeC(&C[(size_t)(row+r)*N + col], acc[mi][nj][r]);
          else ((float*)C)[(size_t)ks*pstride + (size_t)(row+r)*N + col] = acc[mi][nj][r];
        }
      }
    }
}

// standalone gemm8 kernel (down-proj, out-proj)
template<typename OutT, int S, int EPI>
__global__ __launch_bounds__(512, 2) void gemm8(const ushort* __restrict__ A,
                                                const ushort* __restrict__ Bt,
                                                OutT* __restrict__ C,
                                                int M, int N, int Kfull, int pstride) {
  __shared__ ushort sm[65536];
  gemm8_body<OutT,S,EPI>(sm, A, Bt, C, M, N, Kfull, pstride, blockIdx.x, gridDim.x);
}

// fused q-up (blocks 0..255, EPI 0) + kv-up (blocks 256..703, EPI 2)
__global__ __launch_bounds__(512, 2) void gemm_up_dual(const ushort* __restrict__ qn,
                                                       const ushort* __restrict__ wtqb,
                                                       ushort* __restrict__ q,
                                                       const ushort* __restrict__ kvn,
                                                       const ushort* __restrict__ wtkvb) {
  __shared__ ushort sm[65536];
  if (blockIdx.x < 256)
    gemm8_body<ushort,1,0>(sm, qn, wtqb, q, T_, HDQ_, QL_, 0, blockIdx.x, 256);
  else
    gemm8_body<ushort,1,2>(sm, kvn, wtkvb, (ushort*)nullptr, T_, HDKV_, DKV_, 0, blockIdx.x - 256, 448);
}

// ---------------- split-K reduce for out-projection ----------------
__global__ __launch_bounds__(256) void reduce5(const float* __restrict__ p, float* __restrict__ out) {
  size_t i = ((size_t)blockIdx.x*256 + threadIdx.x)*4;
  float4 a = *(const float4*)(p + i);
  #pragma unroll
  for (int s=1; s<SK5_; s++) {
    float4 b = *(const float4*)(p + (size_t)s*MN5_ + i);
    a.x+=b.x; a.y+=b.y; a.z+=b.z; a.w+=b.w;
  }
  *(float4*)(out + i) = a;
}

// ---------------- rmsnorm for q lora (fused SK1_-way reduce, combined partials) ----------------
__global__ __launch_bounds__(256) void rmsnorm_q(const float* __restrict__ p,
                                                 const float* __restrict__ wln) {
  const int row = blockIdx.x;
  const float* x = p + (size_t)row*NKC_;
  float* xo = g_qa + (size_t)row*QL_;
  float ss = 0.f;
  for (int i = threadIdx.x; i < QL_/4; i += 256) {
    float4 v = *(const float4*)(x + i*4);
    #pragma unroll
    for (int s=1; s<SK1_; s++) {
      float4 b = *(const float4*)(x + (size_t)s*PS1_ + i*4);
      v.x+=b.x; v.y+=b.y; v.z+=b.z; v.w+=b.w;
    }
    ((float4*)xo)[i] = v;
    ss += v.x*v.x + v.y*v.y + v.z*v.z + v.w*v.w;
  }
  #pragma unroll
  for (int o=32;o>=1;o>>=1) ss += __shfl_xor(ss, o);
  __shared__ float sr[4];
  if ((threadIdx.x & 63) == 0) sr[threadIdx.x>>6] = ss;
  __syncthreads();
  float rs = rsqrtf((sr[0]+sr[1]+sr[2]+sr[3])/(float)QL_ + 1e-6f);
  for (int i = threadIdx.x; i < QL_; i += 256)
    g_qn[(size_t)row*QL_ + i] = f2b(xo[i]*rs*wln[i]);
}

// ---------------- kv latent rmsnorm + k_pe rope (writes k_pe into g_k for all heads) ----------------
__global__ __launch_bounds__(256) void kv_norm_rope(const float* __restrict__ p,
                                                    const float* __restrict__ wln,
                                                    const int* __restrict__ pos) {
  const int t = blockIdx.x;
  const float* base = p + (size_t)t*NKC_ + QL_;   // combined cols 2048..2623
  __shared__ float lat[NKV_];
  float ss = 0.f;
  for (int i = threadIdx.x; i < NKV_; i += 256) {
    float v = base[i];
    #pragma unroll
    for (int s=1; s<SK1_; s++) v += base[(size_t)s*PS1_ + i];
    lat[i] = v;
    if (i < DKV_) ss += v*v;
  }
  #pragma unroll
  for (int o=32;o>=1;o>>=1) ss += __shfl_xor(ss, o);
  __shared__ float sr[4];
  if ((threadIdx.x & 63) == 0) sr[threadIdx.x>>6] = ss;
  __syncthreads();                                 // covers lat[] too
  float rs = rsqrtf((sr[0]+sr[1]+sr[2]+sr[3])/(float)DKV_ + 1e-6f);
  for (int i = threadIdx.x; i < DKV_; i += 256)
    g_kvn[(size_t)t*DKV_ + i] = f2b(lat[i]*rs*wln[i]);
  // roped k_pe -> g_k[h][t][192..256) for ALL heads
  {
    const int i = threadIdx.x & 31, hb = threadIdx.x >> 5;   // 8 h-groups
    float pp = (float)pos[t];
    float ang = pp * powf(10000.f, -(float)i/32.f);
    float c = cosf(ang), s = sinf(ang);
    float x1 = lat[DKV_ + i], x2 = lat[DKV_ + 32 + i];
    ushort k1 = f2b(x1*c - x2*s);
    ushort k2 = f2b(x2*c + x1*s);
    #pragma unroll
    for (int hh = 0; hh < 4; ++hh) {
      const int h = hb + hh*8;
      g_k[((size_t)h*T_ + t)*DQ_ + DN_ + i]      = k1;
      g_k[((size_t)h*T_ + t)*DQ_ + DN_ + 32 + i] = k2;
    }
  }
}

// ---------------- q rope (in place on g_q) ----------------
__global__ __launch_bounds__(256) void q_rope(const int* __restrict__ pos) {
  const int t = blockIdx.x;
  __shared__ float cs[32], sn[32];
  if (threadIdx.x < 32) {
    const int i = threadIdx.x;
    float p = (float)pos[t];
    float ang = p * powf(10000.f, -(float)i/32.f);
    cs[i] = cosf(ang); sn[i] = sinf(ang);
  }
  __syncthreads();
  for (int e = threadIdx.x; e < NH_*32; e += 256) {
    const int h = e >> 5, i = e & 31;
    ushort* qp = g_q + (size_t)t*HDQ_ + h*DQ_ + DN_;
    float x1 = b2f(qp[i]), x2 = b2f(qp[32 + i]);
    qp[i]      = f2b(x1*cs[i] - x2*sn[i]);
    qp[32 + i] = f2b(x2*cs[i] + x1*sn[i]);
  }
}

// ---------------- build V^T [h][d][t] (64-row tiles via LDS) ----------------
__global__ __launch_bounds__(256) void build_vt() {
  const int h = blockIdx.x, tt = blockIdx.y;
  __shared__ ushort tile[64*272];
  const int tid = threadIdx.x;
  #pragma unroll
  for (int p=0;p<8;p++) {
    int le = (p*256+tid)*8;
    int tl = le >> 8, d = le & 255;
    uint4 v = *(const uint4*)(g_kv + (size_t)(tt*64 + tl)*HDKV_ + h*448 + DN_ + d);
    *(uint4*)(tile + tl*272 + d) = v;
  }
  __syncthreads();
  #pragma unroll
  for (int p=0;p<8;p++) {
    int le = (p*256+tid)*8;
    int d = le >> 6, tl0 = le & 63;
    ushort tmp[8];
    #pragma unroll
    for (int j=0;j<8;j++) tmp[j] = tile[(tl0+j)*272 + d];
    *(uint4*)(g_vt + ((size_t)h*DV_ + d)*T_ + tt*64 + tl0) = *(const uint4*)tmp;
  }
}

// ---------------- flash attention ----------------
// R20 attn = R18 attn EXACTLY (proven 197-199µs, VGPR 168): shared 32KB K/V
// buffer + 4-barrier PIPELINED schedule (STAGE_V flies under softmax,
// STAGE_K under loop-back). R19's separate-buffer 2-barrier variant removed
// the overlap windows and regressed (198->213) — the 4 barriers ARE the
// software pipeline. HARD RULES: no min-waves launch bound (R7/R9/R11 spill
// collapse); no per-lane transcendental prologue (R16); shared KV buffer +
// staggered stages (R19).
__global__ __launch_bounds__(256) void attn_kernel() {
  __shared__ ushort KV[64*256];        // 32KB: K tile [kv][d] OR V^T tile [d][kv]
  __shared__ ushort Pl[4][16][64];     // 8KB per-wave P [q-local][kv]
  const int h = blockIdx.x;
  const int qt = (gridDim.y - 1) - blockIdx.y;     // heavy tiles first
  const int tid = threadIdx.x, lane = tid & 63, w = tid >> 6;
  const int l15 = lane & 15, l4 = lane >> 4;
  const int swm = (l15 & 7) << 3;      // swizzle mask (row = l15 for Pl)

  const ushort* Kh = g_k  + (size_t)h*T_*DQ_;
  const ushort* Vh = g_vt + (size_t)h*DV_*T_;

#define STAGE_K(kt_) do { \
    const ushort* ks_ = Kh + (size_t)(kt_)*64*DQ_; \
    _Pragma("unroll") \
    for (int c_=0;c_<8;c_++){ int le_=(c_*256+tid)*8, r_=le_>>8, co_=le_&255; \
      GLD16(ks_ + r_*256 + (co_ ^ ((r_&7)<<3)), KV+le_); } } while(0)
#define STAGE_V(kt_) do { \
    _Pragma("unroll") \
    for (int c_=0;c_<8;c_++){ int le_=(c_*256+tid)*8, d_=le_>>6, kv_=le_&63; \
      GLD16(Vh + (size_t)d_*T_ + (kt_)*64 + (kv_ ^ ((d_&7)<<3)), KV+le_); } } while(0)

  const int q0 = qt*64;
  const int qrow = q0 + w*16 + l15;                // this lane's q-row

  bf16x8 qf[8];
  {
    const ushort* qb = g_q + (size_t)qrow*HDQ_ + h*DQ_;
    #pragma unroll
    for (int g=0; g<8; g++) qf[g] = *(const bf16x8*)(qb + 32*g + 8*l4);
  }
  f32x4 acc[16];
  #pragma unroll
  for (int i=0;i<16;i++) acc[i] = f32x4{0.f,0.f,0.f,0.f};
  float m_r = -1e30f, l_r = 0.f;

  STAGE_K(0);

  for (int kt = 0; kt <= qt; ++kt) {
    __builtin_amdgcn_sched_barrier(0);
    asm volatile("s_waitcnt vmcnt(0)" ::: "memory");
    __builtin_amdgcn_sched_barrier(0);
    __builtin_amdgcn_s_barrier();                // K[kt] visible to all waves

    // S^T via swapped operands: lane gets S[q=l15][kv=fn*16+l4*4+r]
    f32x4 s[4];
    #pragma unroll
    for (int fn=0; fn<4; fn++) s[fn] = f32x4{0.f,0.f,0.f,0.f};
    __builtin_amdgcn_s_setprio(1);
    #pragma unroll
    for (int g=0; g<8; g++)
      #pragma unroll
      for (int fn=0; fn<4; fn++) {
        bf16x8 kf = *(const bf16x8*)(KV + (fn*16 + l15)*256 + ((32*g + 8*l4) ^ swm));
        s[fn] = __builtin_amdgcn_mfma_f32_16x16x32_bf16(kf, qf[g], s[fn], 0,0,0);
      }
    __builtin_amdgcn_s_setprio(0);
    asm volatile("s_waitcnt lgkmcnt(0)" ::: "memory");
    __builtin_amdgcn_sched_barrier(0);
    __builtin_amdgcn_s_barrier();                // all waves done reading K
    STAGE_V(kt);                                 // V flies under softmax
    __builtin_amdgcn_sched_barrier(0);

    // causal mask (diagonal tile only): kv index is lane-register-local
    if (kt == qt) {
      #pragma unroll
      for (int fn=0; fn<4; fn++)
        #pragma unroll
        for (int r=0;r<4;r++) {
          int kv = kt*64 + fn*16 + l4*4 + r;
          if (kv > qrow) s[fn][r] = -1e30f;
        }
    }

    // online softmax — one q-row per lane: local 16-tree + 2 shuffles
    float mx = s[0][0];
    #pragma unroll
    for (int fn=0; fn<4; fn++)
      #pragma unroll
      for (int r=0;r<4;r++) mx = fmaxf(mx, s[fn][r]);
    mx = fmaxf(mx, __shfl_xor(mx, 16));
    mx = fmaxf(mx, __shfl_xor(mx, 32));
    mx *= SCALE_;
    if (__any(mx > m_r)) {             // rescale only when some row max grew
      float mn = fmaxf(m_r, mx);
      float sc = __expf(m_r - mn);
      m_r = mn;
      l_r *= sc;
      #pragma unroll
      for (int fd=0; fd<16; fd++)
        #pragma unroll
        for (int r=0;r<4;r++) acc[fd][r] *= sc;
    }
    float ssum = 0.f;
    #pragma unroll
    for (int fn=0; fn<4; fn++)
      #pragma unroll
      for (int r=0;r<4;r++) {
        float p = __expf(fmaf(s[fn][r], SCALE_, -m_r));
        s[fn][r] = p; ssum += p;
      }
    ssum += __shfl_xor(ssum, 16);
    ssum += __shfl_xor(ssum, 32);
    l_r += ssum;

    // P -> LDS (intra-wave), 8B vector writes, swizzled on row l15
    #pragma unroll
    for (int fn=0; fn<4; fn++) {
      ushort4 pw;
      pw.x = f2b(s[fn][0]); pw.y = f2b(s[fn][1]);
      pw.z = f2b(s[fn][2]); pw.w = f2b(s[fn][3]);
      *(ushort4*)(&Pl[w][l15][(fn*16 + l4*4) ^ swm]) = pw;
    }

    __builtin_amdgcn_sched_barrier(0);
    asm volatile("s_waitcnt vmcnt(0)" ::: "memory");
    __builtin_amdgcn_sched_barrier(0);
    __builtin_amdgcn_s_barrier();                // V[kt] visible to all waves

    // O^T += V^T P^T  (swapped): lane gets O[q=l15][d=fd*16+l4*4+r]
    __builtin_amdgcn_s_setprio(1);
    #pragma unroll
    for (int s2=0; s2<2; s2++) {
      bf16x8 pa = *(const bf16x8*)(&Pl[w][l15][(s2*32 + 8*l4) ^ swm]);
      #pragma unroll
      for (int fd=0; fd<16; fd++) {
        bf16x8 vb = *(const bf16x8*)(KV + (fd*16 + l15)*64 + ((s2*32 + 8*l4) ^ swm));
        acc[fd] = __builtin_amdgcn_mfma_f32_16x16x32_bf16(vb, pa, acc[fd], 0,0,0);
      }
    }
    __builtin_amdgcn_s_setprio(0);
    asm volatile("s_waitcnt lgkmcnt(0)" ::: "memory");
    __builtin_amdgcn_sched_barrier(0);
    __builtin_amdgcn_s_barrier();                // all waves done reading V
    if (kt < qt) STAGE_K(kt+1);
    __builtin_amdgcn_sched_barrier(0);
  }

  l_r = 1.f / l_r;
  #pragma unroll
  for (int fd=0; fd<16; fd++) {
    ushort4 ow;
    ow.x = f2b(acc[fd][0] * l_r); ow.y = f2b(acc[fd][1] * l_r);
    ow.z = f2b(acc[fd][2] * l_r); ow.w = f2b(acc[fd][3] * l_r);
    *(ushort4*)(g_o + (size_t)qrow*HDV_ + h*DV_ + fd*16 + l4*4) = ow;
  }
#undef STAGE_K
#undef STAGE_V
}

// ---------------- host launch ----------------
extern "C" void kernel_launch(void* const* d_in, const int* in_sizes, int n_in,
                              void* d_out, int out_size, void* d_ws, size_t ws_size,
                              hipStream_t stream) {
  (void)in_sizes; (void)n_in; (void)d_ws; (void)ws_size; (void)out_size;
  const float* hs    = (const float*)d_in[0];
  const int*   pos   = (const int*)  d_in[1];
  const float* wqa   = (const float*)d_in[2];
  const float* qlnw  = (const float*)d_in[3];
  const float* wqb   = (const float*)d_in[4];
  const float* wkva  = (const float*)d_in[5];
  const float* kvlnw = (const float*)d_in[6];
  const float* wkvb  = (const float*)d_in[7];
  const float* wo    = (const float*)d_in[8];
  float* out = (float*)d_out;

  void *p_hb, *p_wtc, *p_wtqb, *p_wtkvb, *p_wto;
  void *p_qn, *p_q, *p_kvn, *p_kv, *p_o, *p_p5;
  hipGetSymbolAddress(&p_hb,    HIP_SYMBOL(g_hb));
  hipGetSymbolAddress(&p_wtc,   HIP_SYMBOL(g_wtc));
  hipGetSymbolAddress(&p_wtqb,  HIP_SYMBOL(g_wtqb));
  hipGetSymbolAddress(&p_wtkvb, HIP_SYMBOL(g_wtkvb));
  hipGetSymbolAddress(&p_wto,   HIP_SYMBOL(g_wto));
  hipGetSymbolAddress(&p_qn,    HIP_SYMBOL(g_qn));
  hipGetSymbolAddress(&p_q,     HIP_SYMBOL(g_q));
  hipGetSymbolAddress(&p_kvn,   HIP_SYMBOL(g_kvn));
  hipGetSymbolAddress(&p_kv,    HIP_SYMBOL(g_kv));
  hipGetSymbolAddress(&p_o,     HIP_SYMBOL(g_o));
  hipGetSymbolAddress(&p_p5,    HIP_SYMBOL(g_p5));

  // 1) hidden convert + ALL weight transposes (one kernel)
  transpose_all<<<41984, 256, 0, stream>>>(hs, wqa, wkva, wqb, wkvb, wo);

  // 2) combined down-projection (q-lora + kv-latent), split-K=4; reduces fused
  gemm8<float,SK1_,1><<<(T_/256)*(NKC_/256)*SK1_, 512, 0, stream>>>((const ushort*)p_hb, (const ushort*)p_wtc, (float*)p_p5, T_, NKC_, HID_, PS1_);
  rmsnorm_q<<<T_, 256, 0, stream>>>((const float*)p_p5, qlnw);
  kv_norm_rope<<<T_, 256, 0, stream>>>((const float*)p_p5, kvlnw, pos);

  // 3) fused up-projections: q-up (256 blocks) + kv-up (448 blocks, k/V routed)
  gemm_up_dual<<<704, 512, 0, stream>>>((const ushort*)p_qn, (const ushort*)p_wtqb, (ushort*)p_q,
                                        (const ushort*)p_kvn, (const ushort*)p_wtkvb);
  q_rope<<<T_, 256, 0, stream>>>(pos);

  // 4) attention prep + attention (one q-tile per block, heavy first)
  build_vt<<<dim3(NH_, T_/64), 256, 0, stream>>>();
  attn_kernel<<<dim3(NH_, 32), 256, 0, stream>>>();

  // 5) output projection (split-K=2) + reduce
  gemm8<float,SK5_,1><<<(T_/256)*(HID_/256)*SK5_, 512, 0, stream>>>((const ushort*)p_o, (const ushort*)p_wto, (float*)p_p5, T_, HID_, HDV_, MN5_);
  reduce5<<<MN5_/1024, 256, 0, stream>>>((const float*)p_p5, out);
}